// Round 20
// baseline (150.139 us; speedup 1.0000x reference)
//
#include <hip/hip_runtime.h>
#include <hip/hip_bf16.h>

typedef __attribute__((ext_vector_type(8))) short bf16x8;
typedef __attribute__((ext_vector_type(4))) float f32x4;

constexpr int Bb = 32, Kk = 8, Ss = 512, HS = 256;
constexpr int SUB = 32;                    // tile rows (= expert block rows)
constexpr int NST = Ss / SUB;              // 16 tiles per (b,k)
constexpr int SUB_BYTES = SUB * HS * 2;    // 16 KB bf16 tile

__device__ __forceinline__ unsigned short f2bf(float f) {
  unsigned int u = __builtin_bit_cast(unsigned int, f);
  u = (u + 0x7FFFu + ((u >> 16) & 1u)) >> 16;
  return (unsigned short)u;
}

__device__ __forceinline__ void gload_lds16(const void* g, void* l) {
  __builtin_amdgcn_global_load_lds((const __attribute__((address_space(1))) void*)g,
                                   (__attribute__((address_space(3))) void*)l, 16, 0, 0);
}

// ---- fused prep: blocks [0,256) pack W1, [256,512) pack W2,
//      [512, 512+4608) ret->bf16 swizzled tiles + partial column sums ----
__global__ void prep(const float* __restrict__ rem, const float* __restrict__ ret,
                     const float* __restrict__ W1, const float* __restrict__ W2,
                     unsigned short* __restrict__ W1p, unsigned short* __restrict__ W2p,
                     char* __restrict__ swz, float* __restrict__ partial_ret,
                     float* __restrict__ partial_rem) {
  int blk = blockIdx.x, t = threadIdx.x;
  if (blk < 512) {
    const float* W = (blk < 256) ? W1 : W2;
    unsigned short* Wp = (blk < 256) ? W1p : W2p;
    int idx = (blk & 255) * 256 + t;
    int lane = idx & 63, nt = (idx >> 6) & 15, kk = (idx >> 10) & 7, k = idx >> 13;
    const float* src = W + ((size_t)k * HS + kk * 32 + ((lane >> 4) * 8)) * HS + nt * 16 + (lane & 15);
    unsigned short* dst = Wp + (size_t)idx * 8;
#pragma unroll
    for (int i = 0; i < 8; ++i) dst[i] = f2bf(src[(size_t)i * HS]);
    return;
  }
  blk -= 512;
  const float* src;
  float* pdst;
  char* dst = nullptr;
  if (blk < Bb * Kk * NST) {
    int st = blk & 15, bk = blk >> 4;
    src = ret + ((size_t)bk * Ss + st * SUB) * HS;
    pdst = partial_ret + (size_t)blk * HS;
    if (swz) dst = swz + (size_t)blk * SUB_BYTES;
  } else {
    int rid = blk - Bb * Kk * NST;
    int st = rid & 15, b = rid >> 4;
    src = rem + ((size_t)b * Ss + st * SUB) * HS;
    pdst = partial_rem + (size_t)rid * HS;
  }
  f32x4 acc = {0.f, 0.f, 0.f, 0.f};
#pragma unroll
  for (int j = 0; j < 8; ++j) {
    int f = j * 256 + t;
    int row = f >> 6, c4 = f & 63;
    f32x4 v = *reinterpret_cast<const f32x4*>(src + (size_t)row * HS + c4 * 4);
    acc += v;
    if (dst) {
      union { unsigned short h[4]; unsigned long long u; } pk;
      pk.h[0] = f2bf(v[0]); pk.h[1] = f2bf(v[1]); pk.h[2] = f2bf(v[2]); pk.h[3] = f2bf(v[3]);
      int off = (c4 >> 5) * 8192 + row * 256 + ((((c4 & 31) >> 1) ^ (row & 7)) * 16) + (c4 & 1) * 8;
      *reinterpret_cast<unsigned long long*>(dst + off) = pk.u;
    }
  }
  __shared__ f32x4 red[256];
  red[t] = acc;
  __syncthreads();
  if (t < 64) {
    f32x4 s = red[t] + red[t + 64] + red[t + 128] + red[t + 192];
    *reinterpret_cast<f32x4*>(pdst + t * 4) = s;
  }
}

// ---- fused experts v20: v17 schedule x v13 geometry.
//      MT=32, grid 512 (2 blocks/CU), 8 waves N-split (wave: 32 cols x 32 rows).
//      Per iter: w1f burst (L2) -> stage(k+1) (stays in flight) -> GEMM1' ->
//      w2f burst -> epi (r_k folded) -> B1 (lgkm) -> GEMM2 (C-in) -> B2.
//      In-kernel routing. LDS ~57.4 KB. No launch_bounds cap beyond (512,1). ----
template <int SRC>
__launch_bounds__(512, 1)
__global__ void experts_kernel(const float* __restrict__ ret, const char* __restrict__ ret_swz,
                               const unsigned short* __restrict__ W1p,
                               const unsigned short* __restrict__ W2p,
                               const float* __restrict__ b1, const float* __restrict__ b2,
                               const float* __restrict__ partial_ret,
                               const float* __restrict__ partial_rem,
                               const float* __restrict__ Wr, const float* __restrict__ br,
                               const float* __restrict__ Wt, const float* __restrict__ bt,
                               float* __restrict__ out) {
  __shared__ __align__(16) char A_lds[2][SUB_BYTES];  // 2 x 16 KB swizzled images
  __shared__ __align__(16) char H_lds[SUB_BYTES];     // 16 KB
  __shared__ float srem_sh[HS];
  __shared__ float sret_sh[Kk][HS];
  __shared__ float shred[8];
  __shared__ float scores_sh[Kk];
  __shared__ float routing_sh[Kk];

  const int blk = blockIdx.x;      // b*16 + st
  const int b = blk >> 4, st = blk & 15;
  const int tid = threadIdx.x;
  const int wave = tid >> 6, lane = tid & 63;
  const int l15 = lane & 15, l4 = lane >> 4;
  const int t256 = tid & 255, half = tid >> 8;

  auto stage = [&](int k, int bufi) {
    if constexpr (SRC == 0) {
      const char* tb = ret_swz + ((size_t)((b * Kk + k) * NST + st)) * SUB_BYTES;
#pragma unroll
      for (int i = 0; i < 2; ++i) {
        int c = wave + i * 8;  // 16 chunks of 1 KB
        gload_lds16(tb + c * 1024 + (size_t)lane * 16, A_lds[bufi] + c * 1024);
      }
    } else {
      const float* src = ret + ((size_t)(b * Kk + k) * Ss + st * SUB) * HS;
#pragma unroll
      for (int j = 0; j < 4; ++j) {
        int f = j * 512 + tid;
        int row = f >> 6, c4 = f & 63;
        f32x4 v = *reinterpret_cast<const f32x4*>(src + (size_t)row * HS + c4 * 4);
        union { unsigned short h[4]; unsigned long long u; } pk;
        pk.h[0] = f2bf(v[0]); pk.h[1] = f2bf(v[1]); pk.h[2] = f2bf(v[2]); pk.h[3] = f2bf(v[3]);
        int off = (c4 >> 5) * 8192 + row * 256 + ((((c4 & 31) >> 1) ^ (row & 7)) * 16) + (c4 & 1) * 8;
        *reinterpret_cast<unsigned long long*>(A_lds[bufi] + off) = pk.u;
      }
    }
  };

  stage(0, 0);  // latency overlaps the routing prologue

  // ---- in-kernel routing for this b (half 0: experts 0-3; half 1: 4-7 + rem) ----
  {
#pragma unroll
    for (int kk = 0; kk < 4; ++kk) {
      int k = half * 4 + kk;
      float sk = 0.f;
      for (int s2 = 0; s2 < NST; ++s2)
        sk += partial_ret[((size_t)((b * Kk + k) * NST + s2)) * HS + t256];
      sret_sh[k][t256] = sk;
    }
    if (half == 1) {
      float s_ = 0.f;
      for (int s2 = 0; s2 < NST; ++s2)
        s_ += partial_rem[((size_t)(b * NST + s2)) * HS + t256];
      srem_sh[t256] = s_;
    }
    __syncthreads();

    float rl = 0.f;
    float tl[4] = {0.f, 0.f, 0.f, 0.f};
    for (int e = 0; e < HS; ++e) {
      float wr = Wr[(size_t)e * HS + t256];
      float wt = Wt[(size_t)e * HS + t256];
      rl += srem_sh[e] * wr;
#pragma unroll
      for (int kk = 0; kk < 4; ++kk) tl[kk] += sret_sh[half * 4 + kk][e] * wt;
    }
    rl = rl * (1.f / Ss) + br[t256];

    for (int kk = 0; kk < 4; ++kk) {
      float p = rl * (tl[kk] * (1.f / Ss) + bt[t256]);
#pragma unroll
      for (int off = 32; off; off >>= 1) p += __shfl_down(p, off);
      if (lane == 0) shred[wave] = p;
      __syncthreads();
      if (tid == 0) scores_sh[kk] = shred[0] + shred[1] + shred[2] + shred[3];
      else if (tid == 256) scores_sh[4 + kk] = shred[4] + shred[5] + shred[6] + shred[7];
      __syncthreads();
    }
    if (tid == 0) {
      float mx = scores_sh[0];
      for (int k = 1; k < Kk; ++k) mx = fmaxf(mx, scores_sh[k]);
      float ssum = 0.f, ev[Kk];
      for (int k = 0; k < Kk; ++k) { ev[k] = expf(scores_sh[k] - mx); ssum += ev[k]; }
      for (int k = 0; k < Kk; ++k) routing_sh[k] = ev[k] / ssum;
    }
  }
  asm volatile("s_waitcnt vmcnt(0) lgkmcnt(0)\n\ts_barrier" ::: "memory");

  f32x4 out_acc[2][2];
#pragma unroll
  for (int m = 0; m < 2; ++m)
#pragma unroll
    for (int n = 0; n < 2; ++n) out_acc[m][n] = {0.f, 0.f, 0.f, 0.f};
  const f32x4 zero4 = {0.f, 0.f, 0.f, 0.f};

  int buf = 0;
  for (int k = 0; k < Kk; ++k) {
    // ---- w1f burst first (L2): GEMM1 waits these with vmcnt(2), stage stays in flight ----
    const unsigned short* W1k = W1p + (size_t)k * 65536;
    bf16x8 w1f[8][2];
#pragma unroll
    for (int kk = 0; kk < 8; ++kk)
#pragma unroll
      for (int m = 0; m < 2; ++m)
        w1f[kk][m] = *reinterpret_cast<const bf16x8*>(
            W1k + ((size_t)(kk * 16 + wave * 2 + m) * 64 + lane) * 8);

    // ---- stage(k+1) AFTER w1f ----
    if (k + 1 < Kk) stage(k + 1, buf ^ 1);

    // ---- GEMM1': H^T = W1^T(A-op) x A^T(B-op); wave owns e in [wave*32,+32) ----
    f32x4 accH[2][2];
#pragma unroll
    for (int m = 0; m < 2; ++m)
#pragma unroll
      for (int n = 0; n < 2; ++n) accH[m][n] = zero4;

#pragma unroll
    for (int kk = 0; kk < 8; ++kk) {
      bf16x8 aA[2];
#pragma unroll
      for (int n = 0; n < 2; ++n) {
        int srow = n * 16 + l15;
        int off = (kk >> 2) * 8192 + srow * 256 + ((((kk & 3) * 4 + l4) ^ (srow & 7)) * 16);
        aA[n] = *reinterpret_cast<const bf16x8*>(A_lds[buf] + off);
      }
#pragma unroll
      for (int m = 0; m < 2; ++m)
#pragma unroll
        for (int n = 0; n < 2; ++n)
          accH[m][n] = __builtin_amdgcn_mfma_f32_16x16x32_bf16(w1f[kk][m], aA[n], accH[m][n], 0, 0, 0);
    }

    // ---- w2f burst (hides under epilogue + B1) ----
    const unsigned short* W2k = W2p + (size_t)k * 65536;
    bf16x8 w2f[8][2];
#pragma unroll
    for (int kk = 0; kk < 8; ++kk)
#pragma unroll
      for (int n = 0; n < 2; ++n)
        w2f[kk][n] = *reinterpret_cast<const bf16x8*>(
            W2k + ((size_t)(kk * 16 + wave * 2 + n) * 64 + lane) * 8);

    // ---- epilogue1': h = relu(acc + b1) * r_k -> H_lds (bf16, swizzled) ----
    {
      float r = routing_sh[k];
#pragma unroll
      for (int m = 0; m < 2; ++m) {
        int e0 = wave * 32 + m * 16 + l4 * 4;
        float4 b1v = *reinterpret_cast<const float4*>(b1 + k * HS + e0);
#pragma unroll
        for (int n = 0; n < 2; ++n) {
          int srow = n * 16 + l15;
          union { unsigned short h[4]; unsigned long long u; } pk;
          pk.h[0] = f2bf(fmaxf(accH[m][n][0] + b1v.x, 0.f) * r);
          pk.h[1] = f2bf(fmaxf(accH[m][n][1] + b1v.y, 0.f) * r);
          pk.h[2] = f2bf(fmaxf(accH[m][n][2] + b1v.z, 0.f) * r);
          pk.h[3] = f2bf(fmaxf(accH[m][n][3] + b1v.w, 0.f) * r);
          int boff = srow * 512 + ((e0 * 2) ^ ((srow & 7) << 4));
          *reinterpret_cast<unsigned long long*>(H_lds + boff) = pk.u;
        }
      }
    }

    // B1: H visible; A(k) reads done. stage(k+1)+w2f stay in flight (no vmcnt).
    asm volatile("s_waitcnt lgkmcnt(0)\n\ts_barrier" ::: "memory");

    // ---- GEMM2: out_acc += (r_k H) x W2 (direct MFMA C-in accumulate) ----
#pragma unroll
    for (int kk = 0; kk < 8; ++kk) {
      bf16x8 aH[2];
#pragma unroll
      for (int m = 0; m < 2; ++m) {
        int r = m * 16 + l15;
        int boff = r * 512 + ((kk * 64 + l4 * 16) ^ ((r & 7) << 4));
        aH[m] = *reinterpret_cast<const bf16x8*>(H_lds + boff);
      }
#pragma unroll
      for (int m = 0; m < 2; ++m)
#pragma unroll
        for (int n = 0; n < 2; ++n)
          out_acc[m][n] = __builtin_amdgcn_mfma_f32_16x16x32_bf16(aH[m], w2f[kk][n], out_acc[m][n], 0, 0, 0);
    }
    // B2: stage(k+1) landed; H reads done
    asm volatile("s_waitcnt vmcnt(0) lgkmcnt(0)\n\ts_barrier" ::: "memory");
    buf ^= 1;
  }

  // ---- store: out + sum_k r_k * b2[k][col] ----
  float bias2[2];
#pragma unroll
  for (int n = 0; n < 2; ++n) {
    int col = (wave * 2 + n) * 16 + l15;
    float s = 0.f;
#pragma unroll
    for (int k = 0; k < Kk; ++k) s += routing_sh[k] * b2[k * HS + col];
    bias2[n] = s;
  }
#pragma unroll
  for (int m = 0; m < 2; ++m)
#pragma unroll
    for (int i = 0; i < 4; ++i) {
      int row = m * 16 + l4 * 4 + i;
      float* orow = out + ((size_t)b * Ss + st * SUB + row) * HS;
#pragma unroll
      for (int n = 0; n < 2; ++n)
        orow[(wave * 2 + n) * 16 + l15] = out_acc[m][n][i] + bias2[n];
    }
}

extern "C" void kernel_launch(void* const* d_in, const int* in_sizes, int n_in,
                              void* d_out, int out_size, void* d_ws, size_t ws_size,
                              hipStream_t stream) {
  const float* rem = (const float*)d_in[0];
  const float* ret = (const float*)d_in[1];
  const float* Wr  = (const float*)d_in[2];
  const float* br  = (const float*)d_in[3];
  const float* Wt  = (const float*)d_in[4];
  const float* bt  = (const float*)d_in[5];
  const float* W1  = (const float*)d_in[6];
  const float* b1  = (const float*)d_in[7];
  const float* W2  = (const float*)d_in[8];
  const float* b2  = (const float*)d_in[9];
  float* out = (float*)d_out;

  char* w = (char*)d_ws;
  unsigned short* W1p = (unsigned short*)w;                         // 1 MB
  unsigned short* W2p = (unsigned short*)(w + (1u << 20));          // 1 MB
  float* partial_ret  = (float*)(w + (2u << 20));                   // 4 MB (4096 x 256)
  float* partial_rem  = (float*)(w + (6u << 20));                   // 512 KB (512 x 256)
  char*  ret_swz      = w + (7u << 20);                             // 64 MB

  bool full = ws_size >= ((size_t)71 << 20);

  prep<<<512 + Bb * Kk * NST + Bb * NST, 256, 0, stream>>>(rem, ret, W1, W2, W1p, W2p,
                                                           full ? ret_swz : nullptr,
                                                           partial_ret, partial_rem);
  if (full)
    experts_kernel<0><<<Bb * NST, 512, 0, stream>>>(ret, ret_swz, W1p, W2p, b1, b2,
                                                    partial_ret, partial_rem,
                                                    Wr, br, Wt, bt, out);
  else
    experts_kernel<1><<<Bb * NST, 512, 0, stream>>>(ret, nullptr, W1p, W2p, b1, b2,
                                                    partial_ret, partial_rem,
                                                    Wr, br, Wt, bt, out);
}

// Round 21
// 96.225 us; speedup vs baseline: 1.5603x; 1.5603x over previous
//
#include <hip/hip_runtime.h>
#include <hip/hip_bf16.h>

typedef __attribute__((ext_vector_type(8))) short bf16x8;
typedef __attribute__((ext_vector_type(4))) float f32x4;

constexpr int Bb = 32, Kk = 8, Ss = 512, HS = 256;
constexpr int SUB = 32;                    // prep subtile rows
constexpr int NST = Ss / SUB;              // 16 subtiles per (b,k)
constexpr int SUB_BYTES = SUB * HS * 2;    // 16 KB bf16 subtile
constexpr int MT = 64;                     // expert block rows (2 subtiles)

__device__ __forceinline__ unsigned short f2bf(float f) {
  unsigned int u = __builtin_bit_cast(unsigned int, f);
  u = (u + 0x7FFFu + ((u >> 16) & 1u)) >> 16;
  return (unsigned short)u;
}

__device__ __forceinline__ void gload_lds16(const void* g, void* l) {
  __builtin_amdgcn_global_load_lds((const __attribute__((address_space(1))) void*)g,
                                   (__attribute__((address_space(3))) void*)l, 16, 0, 0);
}

// ---- fused prep: blocks [0,256) pack W1, [256,512) pack W2,
//      [512, 512+4608) ret->bf16 swizzled subtiles + partial column sums ----
__global__ void prep(const float* __restrict__ rem, const float* __restrict__ ret,
                     const float* __restrict__ W1, const float* __restrict__ W2,
                     unsigned short* __restrict__ W1p, unsigned short* __restrict__ W2p,
                     char* __restrict__ swz, float* __restrict__ partial_ret,
                     float* __restrict__ partial_rem) {
  int blk = blockIdx.x, t = threadIdx.x;
  if (blk < 512) {
    const float* W = (blk < 256) ? W1 : W2;
    unsigned short* Wp = (blk < 256) ? W1p : W2p;
    int idx = (blk & 255) * 256 + t;
    int lane = idx & 63, nt = (idx >> 6) & 15, kk = (idx >> 10) & 7, k = idx >> 13;
    const float* src = W + ((size_t)k * HS + kk * 32 + ((lane >> 4) * 8)) * HS + nt * 16 + (lane & 15);
    unsigned short* dst = Wp + (size_t)idx * 8;
#pragma unroll
    for (int i = 0; i < 8; ++i) dst[i] = f2bf(src[(size_t)i * HS]);
    return;
  }
  blk -= 512;
  const float* src;
  float* pdst;
  char* dst = nullptr;
  if (blk < Bb * Kk * NST) {
    int st = blk & 15, bk = blk >> 4;
    src = ret + ((size_t)bk * Ss + st * SUB) * HS;
    pdst = partial_ret + (size_t)blk * HS;
    if (swz) dst = swz + (size_t)blk * SUB_BYTES;
  } else {
    int rid = blk - Bb * Kk * NST;
    int st = rid & 15, b = rid >> 4;
    src = rem + ((size_t)b * Ss + st * SUB) * HS;
    pdst = partial_rem + (size_t)rid * HS;
  }
  f32x4 acc = {0.f, 0.f, 0.f, 0.f};
#pragma unroll
  for (int j = 0; j < 8; ++j) {
    int f = j * 256 + t;
    int row = f >> 6, c4 = f & 63;
    f32x4 v = *reinterpret_cast<const f32x4*>(src + (size_t)row * HS + c4 * 4);
    acc += v;
    if (dst) {
      union { unsigned short h[4]; unsigned long long u; } pk;
      pk.h[0] = f2bf(v[0]); pk.h[1] = f2bf(v[1]); pk.h[2] = f2bf(v[2]); pk.h[3] = f2bf(v[3]);
      int off = (c4 >> 5) * 8192 + row * 256 + ((((c4 & 31) >> 1) ^ (row & 7)) * 16) + (c4 & 1) * 8;
      *reinterpret_cast<unsigned long long*>(dst + off) = pk.u;
    }
  }
  __shared__ f32x4 red[256];
  red[t] = acc;
  __syncthreads();
  if (t < 64) {
    f32x4 s = red[t] + red[t + 64] + red[t + 128] + red[t + 192];
    *reinterpret_cast<f32x4*>(pdst + t * 4) = s;
  }
}

// ---- fused experts v21: v17 schedule at 2 blocks/CU.
//      Single A buffer (32 KB) + H (32 KB) + routing scratch -> ~75 KB LDS.
//      Per iter: w1f burst (L2) -> GEMM1' -> w2f burst -> epi (r_k folded) ->
//      B1 (lgkm-only) -> stage(k+1) issue (hides under GEMM2) -> GEMM2 (C-in)
//      -> B2 (vm+lgkm). In-kernel routing. No VGPR cap: must land <=128. ----
template <int SRC>
__launch_bounds__(512, 1)
__global__ void experts_kernel(const float* __restrict__ ret, const char* __restrict__ ret_swz,
                               const unsigned short* __restrict__ W1p,
                               const unsigned short* __restrict__ W2p,
                               const float* __restrict__ b1, const float* __restrict__ b2,
                               const float* __restrict__ partial_ret,
                               const float* __restrict__ partial_rem,
                               const float* __restrict__ Wr, const float* __restrict__ br,
                               const float* __restrict__ Wt, const float* __restrict__ bt,
                               float* __restrict__ out) {
  __shared__ __align__(16) char A_lds[2 * SUB_BYTES];  // 32 KB swizzled image (single buffer)
  __shared__ __align__(16) char H_lds[MT * HS * 2];    // 32 KB, row*512B, XOR-swizzled
  __shared__ float srem_sh[HS];
  __shared__ float sret_sh[Kk][HS];
  __shared__ float shred[8];
  __shared__ float scores_sh[Kk];
  __shared__ float routing_sh[Kk];

  const int blk = blockIdx.x;      // b*8 + st64
  const int b = blk >> 3, st64 = blk & 7;
  const int tid = threadIdx.x;
  const int wave = tid >> 6, lane = tid & 63;
  const int l15 = lane & 15, l4 = lane >> 4;
  const int t256 = tid & 255, half = tid >> 8;

  auto stage = [&](int k) {
    if constexpr (SRC == 0) {
      const char* tb = ret_swz + ((size_t)((b * Kk + k) * NST + st64 * 2)) * SUB_BYTES;
#pragma unroll
      for (int i = 0; i < 4; ++i) {
        int c = wave + i * 8;  // 32 chunks of 1 KB
        gload_lds16(tb + c * 1024 + (size_t)lane * 16, A_lds + c * 1024);
      }
    } else {
      const float* src = ret + ((size_t)(b * Kk + k) * Ss + st64 * MT) * HS;
#pragma unroll
      for (int j = 0; j < 8; ++j) {
        int f = j * 512 + tid;
        int row = f >> 6, c4 = f & 63;
        f32x4 v = *reinterpret_cast<const f32x4*>(src + (size_t)row * HS + c4 * 4);
        union { unsigned short h[4]; unsigned long long u; } pk;
        pk.h[0] = f2bf(v[0]); pk.h[1] = f2bf(v[1]); pk.h[2] = f2bf(v[2]); pk.h[3] = f2bf(v[3]);
        int off = (row >> 5) * 16384 + (c4 >> 5) * 8192 + (row & 31) * 256 +
                  ((((c4 & 31) >> 1) ^ (row & 7)) * 16) + (c4 & 1) * 8;
        *reinterpret_cast<unsigned long long*>(A_lds + off) = pk.u;
      }
    }
  };

  stage(0);  // HBM/L3 latency overlaps the routing prologue below

  // ---- in-kernel routing for this b (half 0: experts 0-3; half 1: 4-7 + rem) ----
  {
#pragma unroll
    for (int kk = 0; kk < 4; ++kk) {
      int k = half * 4 + kk;
      float sk = 0.f;
      for (int st = 0; st < NST; ++st)
        sk += partial_ret[((size_t)((b * Kk + k) * NST + st)) * HS + t256];
      sret_sh[k][t256] = sk;
    }
    if (half == 1) {
      float s_ = 0.f;
      for (int st = 0; st < NST; ++st)
        s_ += partial_rem[((size_t)(b * NST + st)) * HS + t256];
      srem_sh[t256] = s_;
    }
    __syncthreads();

    float rl = 0.f;
    float tl[4] = {0.f, 0.f, 0.f, 0.f};
    for (int e = 0; e < HS; ++e) {
      float wr = Wr[(size_t)e * HS + t256];
      float wt = Wt[(size_t)e * HS + t256];
      rl += srem_sh[e] * wr;
#pragma unroll
      for (int kk = 0; kk < 4; ++kk) tl[kk] += sret_sh[half * 4 + kk][e] * wt;
    }
    rl = rl * (1.f / Ss) + br[t256];

    for (int kk = 0; kk < 4; ++kk) {
      float p = rl * (tl[kk] * (1.f / Ss) + bt[t256]);
#pragma unroll
      for (int off = 32; off; off >>= 1) p += __shfl_down(p, off);
      if (lane == 0) shred[wave] = p;
      __syncthreads();
      if (tid == 0) scores_sh[kk] = shred[0] + shred[1] + shred[2] + shred[3];
      else if (tid == 256) scores_sh[4 + kk] = shred[4] + shred[5] + shred[6] + shred[7];
      __syncthreads();
    }
    if (tid == 0) {
      float mx = scores_sh[0];
      for (int k = 1; k < Kk; ++k) mx = fmaxf(mx, scores_sh[k]);
      float ssum = 0.f, ev[Kk];
      for (int k = 0; k < Kk; ++k) { ev[k] = expf(scores_sh[k] - mx); ssum += ev[k]; }
      for (int k = 0; k < Kk; ++k) routing_sh[k] = ev[k] / ssum;
    }
  }
  // drains stage(0) + routing LDS, publishes routing_sh
  asm volatile("s_waitcnt vmcnt(0) lgkmcnt(0)\n\ts_barrier" ::: "memory");

  f32x4 out_acc[4][2];
#pragma unroll
  for (int m = 0; m < 4; ++m)
#pragma unroll
    for (int n = 0; n < 2; ++n) out_acc[m][n] = {0.f, 0.f, 0.f, 0.f};
  const f32x4 zero4 = {0.f, 0.f, 0.f, 0.f};

  for (int k = 0; k < Kk; ++k) {
    // ---- bulk-hoist W1 fragments (L2-resident, one burst, one latency) ----
    const unsigned short* W1k = W1p + (size_t)k * 65536;
    bf16x8 w1f[8][2];
#pragma unroll
    for (int kk = 0; kk < 8; ++kk)
#pragma unroll
      for (int m = 0; m < 2; ++m)
        w1f[kk][m] = *reinterpret_cast<const bf16x8*>(
            W1k + ((size_t)(kk * 16 + wave * 2 + m) * 64 + lane) * 8);

    // ---- GEMM1': H^T = W1^T(A-op) x A^T(B-op); wave owns e in [wave*32,+32) ----
    f32x4 accH[2][4];
#pragma unroll
    for (int m = 0; m < 2; ++m)
#pragma unroll
      for (int n = 0; n < 4; ++n) accH[m][n] = zero4;

#pragma unroll
    for (int kk = 0; kk < 8; ++kk) {
      bf16x8 aA[4];
#pragma unroll
      for (int n = 0; n < 4; ++n) {
        int srow = n * 16 + l15;
        int r5 = srow & 31;
        int off = (srow >> 5) * 16384 + (kk >> 2) * 8192 + r5 * 256 +
                  ((((kk & 3) * 4 + l4) ^ (r5 & 7)) * 16);
        aA[n] = *reinterpret_cast<const bf16x8*>(A_lds + off);
      }
#pragma unroll
      for (int m = 0; m < 2; ++m)
#pragma unroll
        for (int n = 0; n < 4; ++n)
          accH[m][n] = __builtin_amdgcn_mfma_f32_16x16x32_bf16(w1f[kk][m], aA[n], accH[m][n], 0, 0, 0);
    }

    // ---- w2f burst: hides under epilogue + B1; older than stage(k+1) so
    //      GEMM2's w2f waits do NOT drain the staging loads ----
    const unsigned short* W2k = W2p + (size_t)k * 65536;
    bf16x8 w2f[8][2];
#pragma unroll
    for (int kk = 0; kk < 8; ++kk)
#pragma unroll
      for (int n = 0; n < 2; ++n)
        w2f[kk][n] = *reinterpret_cast<const bf16x8*>(
            W2k + ((size_t)(kk * 16 + wave * 2 + n) * 64 + lane) * 8);

    // ---- epilogue1': h = relu(acc + b1) * r_k -> H_lds (bf16, swizzled) ----
    {
      float r = routing_sh[k];
#pragma unroll
      for (int m = 0; m < 2; ++m) {
        int e0 = wave * 32 + m * 16 + l4 * 4;
        float4 b1v = *reinterpret_cast<const float4*>(b1 + k * HS + e0);
#pragma unroll
        for (int n = 0; n < 4; ++n) {
          int srow = n * 16 + l15;
          union { unsigned short h[4]; unsigned long long u; } pk;
          pk.h[0] = f2bf(fmaxf(accH[m][n][0] + b1v.x, 0.f) * r);
          pk.h[1] = f2bf(fmaxf(accH[m][n][1] + b1v.y, 0.f) * r);
          pk.h[2] = f2bf(fmaxf(accH[m][n][2] + b1v.z, 0.f) * r);
          pk.h[3] = f2bf(fmaxf(accH[m][n][3] + b1v.w, 0.f) * r);
          int boff = srow * 512 + ((e0 * 2) ^ ((srow & 7) << 4));
          *reinterpret_cast<unsigned long long*>(H_lds + boff) = pk.u;
        }
      }
    }

    // B1: H visible; all A(k) reads done (lgkm-only: w2f stays in flight)
    asm volatile("s_waitcnt lgkmcnt(0)\n\ts_barrier" ::: "memory");

    // ---- stage(k+1): A buffer free now; HBM latency hides under GEMM2 ----
    if (k + 1 < Kk) stage(k + 1);

    // ---- GEMM2: out_acc += (r_k H) x W2 (direct MFMA C-in accumulate) ----
#pragma unroll
    for (int kk = 0; kk < 8; ++kk) {
      bf16x8 aH[4];
#pragma unroll
      for (int m = 0; m < 4; ++m) {
        int r = m * 16 + l15;
        int boff = r * 512 + ((kk * 64 + l4 * 16) ^ ((r & 7) << 4));
        aH[m] = *reinterpret_cast<const bf16x8*>(H_lds + boff);
      }
#pragma unroll
      for (int m = 0; m < 4; ++m)
#pragma unroll
        for (int n = 0; n < 2; ++n)
          out_acc[m][n] = __builtin_amdgcn_mfma_f32_16x16x32_bf16(aH[m], w2f[kk][n], out_acc[m][n], 0, 0, 0);
    }
    // B2: stage(k+1) landed; H reads done (safe to rewrite A/H next iter)
    asm volatile("s_waitcnt vmcnt(0) lgkmcnt(0)\n\ts_barrier" ::: "memory");
  }

  // ---- store: out + sum_k r_k * b2[k][col] ----
  float bias2[2];
#pragma unroll
  for (int n = 0; n < 2; ++n) {
    int col = (wave * 2 + n) * 16 + l15;
    float s = 0.f;
#pragma unroll
    for (int k = 0; k < Kk; ++k) s += routing_sh[k] * b2[k * HS + col];
    bias2[n] = s;
  }
#pragma unroll
  for (int m = 0; m < 4; ++m)
#pragma unroll
    for (int i = 0; i < 4; ++i) {
      int row = m * 16 + l4 * 4 + i;
      float* orow = out + ((size_t)b * Ss + st64 * MT + row) * HS;
#pragma unroll
      for (int n = 0; n < 2; ++n)
        orow[(wave * 2 + n) * 16 + l15] = out_acc[m][n][i] + bias2[n];
    }
}

extern "C" void kernel_launch(void* const* d_in, const int* in_sizes, int n_in,
                              void* d_out, int out_size, void* d_ws, size_t ws_size,
                              hipStream_t stream) {
  const float* rem = (const float*)d_in[0];
  const float* ret = (const float*)d_in[1];
  const float* Wr  = (const float*)d_in[2];
  const float* br  = (const float*)d_in[3];
  const float* Wt  = (const float*)d_in[4];
  const float* bt  = (const float*)d_in[5];
  const float* W1  = (const float*)d_in[6];
  const float* b1  = (const float*)d_in[7];
  const float* W2  = (const float*)d_in[8];
  const float* b2  = (const float*)d_in[9];
  float* out = (float*)d_out;

  char* w = (char*)d_ws;
  unsigned short* W1p = (unsigned short*)w;                         // 1 MB
  unsigned short* W2p = (unsigned short*)(w + (1u << 20));          // 1 MB
  float* partial_ret  = (float*)(w + (2u << 20));                   // 4 MB (4096 x 256)
  float* partial_rem  = (float*)(w + (6u << 20));                   // 512 KB (512 x 256)
  char*  ret_swz      = w + (7u << 20);                             // 64 MB

  bool full = ws_size >= ((size_t)71 << 20);

  prep<<<512 + Bb * Kk * NST + Bb * NST, 256, 0, stream>>>(rem, ret, W1, W2, W1p, W2p,
                                                           full ? ret_swz : nullptr,
                                                           partial_ret, partial_rem);
  if (full)
    experts_kernel<0><<<Bb * (Ss / MT), 512, 0, stream>>>(ret, ret_swz, W1p, W2p, b1, b2,
                                                          partial_ret, partial_rem,
                                                          Wr, br, Wt, bt, out);
  else
    experts_kernel<1><<<Bb * (Ss / MT), 512, 0, stream>>>(ret, nullptr, W1p, W2p, b1, b2,
                                                          partial_ret, partial_rem,
                                                          Wr, br, Wt, bt, out);
}